// Round 2
// baseline (1005.555 us; speedup 1.0000x reference)
//
#include <hip/hip_runtime.h>

#define T_STEPS 2000
#define NBATCH  256
#define HID     51
#define FEAT    49
#define ROWF4   784                         // float4 per 64-step chunk (64*49/4)
#define XTOT4   (NBATCH * T_STEPS * FEAT / 4)

typedef _Float16 v2h __attribute__((ext_vector_type(2)));

__device__ __forceinline__ float rl(float v, int lane) {
    return __int_as_float(__builtin_amdgcn_readlane(__float_as_int(v), lane));
}
__device__ __forceinline__ int rli(int v, int lane) {
    return __builtin_amdgcn_readlane(v, lane);
}
__device__ __forceinline__ float sigmoidf_fast(float x) {
    return __builtin_amdgcn_rcpf(1.0f + __builtin_amdgcn_exp2f(-1.4426950408889634f * x));
}
__device__ __forceinline__ float tanhf_fast(float x) {
    return 1.0f - 2.0f * __builtin_amdgcn_rcpf(1.0f + __builtin_amdgcn_exp2f(2.8853900817779268f * x));
}
__device__ __forceinline__ int packh2(float lo, float hi) {
    v2h p = (v2h){(_Float16)lo, (_Float16)hi};
    return __builtin_bit_cast(int, p);
}
__device__ __forceinline__ float dot2(int w, int h, float acc) {
    return __builtin_amdgcn_fdot2(__builtin_bit_cast(v2h, w),
                                  __builtin_bit_cast(v2h, h), acc, false);
}
__device__ __forceinline__ float row_dot(const float* row, const float* __restrict__ Wl) {
    float a0 = 0, a1 = 0, a2 = 0, a3 = 0, a4 = 0, a5 = 0, a6 = 0;
#pragma unroll
    for (int j = 0; j < FEAT; j += 7) {
        a0 = fmaf(row[j    ], Wl[j    ], a0);
        a1 = fmaf(row[j + 1], Wl[j + 1], a1);
        a2 = fmaf(row[j + 2], Wl[j + 2], a2);
        a3 = fmaf(row[j + 3], Wl[j + 3], a3);
        a4 = fmaf(row[j + 4], Wl[j + 4], a4);
        a5 = fmaf(row[j + 5], Wl[j + 5], a5);
        a6 = fmaf(row[j + 6], Wl[j + 6], a6);
    }
    return ((a0 + a1) + (a2 + a3)) + ((a4 + a5) + a6);
}

#define REP26(F) F(0) F(1) F(2) F(3) F(4) F(5) F(6) F(7) F(8) F(9) F(10) F(11) F(12) \
                 F(13) F(14) F(15) F(16) F(17) F(18) F(19) F(20) F(21) F(22) F(23) F(24) F(25)

// SINGLE wave per sample. Lane l (<51) owns hidden unit l and computes all 4
// of its gates (i,f,g,o) itself; lane 51 owns LSTM2 (4 gates over h1, with
// Whh2 folded into pair-25-hi). The c/h update is lane-local, so the per-step
// LDS gate exchange and BOTH barriers are gone — the kernel contains zero
// s_barrier. h broadcast is in-wave: cvt_f16 + dpp(r^1) + 26 readlanes.
// Output: lane 51 ds_writes one float/step into ob[]; coalesced 64-wide
// global flush every 64 steps (in-wave lgkmcnt ordering only, no barrier).
__global__ __attribute__((amdgpu_flat_work_group_size(64, 64), amdgpu_waves_per_eu(1)))
void rnn_kernel(
    const float* __restrict__ x,
    const float* __restrict__ Wl, const float* __restrict__ bl,
    const float* __restrict__ Wih1, const float* __restrict__ Whh1,
    const float* __restrict__ bih1, const float* __restrict__ bhh1,
    const float* __restrict__ Wih2, const float* __restrict__ Whh2,
    const float* __restrict__ bih2, const float* __restrict__ bhh2,
    const float* __restrict__ Wa, const float* __restrict__ ba,
    float* __restrict__ out)
{
    const int n    = blockIdx.x;
    const int lane = threadIdx.x;          // 0..63
    float* optr = out + (size_t)n * T_STEPS;
    const float4* x4 = (const float4*)x;
    const int sbase = n * (T_STEPS * FEAT / 4);

    __shared__ float xt_[64 * FEAT];       // 12544 B x-tile (single buffer)
    __shared__ float ob[64];               // 256 B output ring (written by lane 51)
    float4* t4 = (float4*)xt_;

    // ---- weights: 4 gates x 26 packed f16 pairs per lane ----
#define DECLW(j) int w0_##j, w1_##j, w2_##j, w3_##j; int sh_##j;
    REP26(DECLW)

    const float msk = (lane <= HID) ? 1.0f : 0.0f;   // lanes 52..63 masked to 0
    const float m51 = (lane == HID) ? 1.0f : 0.0f;
#define LOADW(j, wv) { float lo = srow[2*(j)] * msk; \
        float hi = (2*(j)+1 < HID) ? srow[2*(j)+1] * msk : wh2; \
        wv##_##j = packh2(lo, hi); asm("" : "+v"(wv##_##j)); }
#define LOADW0(j) LOADW(j, w0)
#define LOADW1(j) LOADW(j, w1)
#define LOADW2(j) LOADW(j, w2)
#define LOADW3(j) LOADW(j, w3)
    { const float* srow = (lane < HID) ? (Whh1 + (0 * HID + lane) * HID) : (Wih2 + 0 * HID);
      const float wh2 = Whh2[0] * m51;  REP26(LOADW0) }
    { const float* srow = (lane < HID) ? (Whh1 + (1 * HID + lane) * HID) : (Wih2 + 1 * HID);
      const float wh2 = Whh2[1] * m51;  REP26(LOADW1) }
    { const float* srow = (lane < HID) ? (Whh1 + (2 * HID + lane) * HID) : (Wih2 + 2 * HID);
      const float wh2 = Whh2[2] * m51;  REP26(LOADW2) }
    { const float* srow = (lane < HID) ? (Whh1 + (3 * HID + lane) * HID) : (Wih2 + 3 * HID);
      const float wh2 = Whh2[3] * m51;  REP26(LOADW3) }

    float wx0 = 0, wx1 = 0, wx2 = 0, wx3 = 0;
    float b0 = 0, b1 = 0, b2 = 0, b3 = 0;
    if (lane < HID) {
        wx0 = Wih1[0 * HID + lane]; b0 = bih1[0 * HID + lane] + bhh1[0 * HID + lane];
        wx1 = Wih1[1 * HID + lane]; b1 = bih1[1 * HID + lane] + bhh1[1 * HID + lane];
        wx2 = Wih1[2 * HID + lane]; b2 = bih1[2 * HID + lane] + bhh1[2 * HID + lane];
        wx3 = Wih1[3 * HID + lane]; b3 = bih1[3 * HID + lane] + bhh1[3 * HID + lane];
    } else if (lane == HID) {
        b0 = bih2[0] + bhh2[0]; b1 = bih2[1] + bhh2[1];
        b2 = bih2[2] + bhh2[2]; b3 = bih2[3] + bhh2[3];
    }
    const float wav = Wa[0], bav = ba[0];
    const float bl0 = bl[0];

#define INITS(j) sh_##j = 0;
    REP26(INITS)

    float c = 0.0f, h = 0.0f;

    // ---- x prefetch: 784 float4 per 64-step chunk over 64 lanes (13 regs) ----
    float4 pf0, pf1, pf2, pf3, pf4, pf5, pf6, pf7, pf8, pf9, pf10, pf11, pf12;
#define PFALL(base) { int g_; \
    g_=(base)+  0+lane; g_=g_<XTOT4?g_:(XTOT4-1); pf0 =x4[g_]; \
    g_=(base)+ 64+lane; g_=g_<XTOT4?g_:(XTOT4-1); pf1 =x4[g_]; \
    g_=(base)+128+lane; g_=g_<XTOT4?g_:(XTOT4-1); pf2 =x4[g_]; \
    g_=(base)+192+lane; g_=g_<XTOT4?g_:(XTOT4-1); pf3 =x4[g_]; \
    g_=(base)+256+lane; g_=g_<XTOT4?g_:(XTOT4-1); pf4 =x4[g_]; \
    g_=(base)+320+lane; g_=g_<XTOT4?g_:(XTOT4-1); pf5 =x4[g_]; \
    g_=(base)+384+lane; g_=g_<XTOT4?g_:(XTOT4-1); pf6 =x4[g_]; \
    g_=(base)+448+lane; g_=g_<XTOT4?g_:(XTOT4-1); pf7 =x4[g_]; \
    g_=(base)+512+lane; g_=g_<XTOT4?g_:(XTOT4-1); pf8 =x4[g_]; \
    g_=(base)+576+lane; g_=g_<XTOT4?g_:(XTOT4-1); pf9 =x4[g_]; \
    g_=(base)+640+lane; g_=g_<XTOT4?g_:(XTOT4-1); pf10=x4[g_]; \
    g_=(base)+704+lane; g_=g_<XTOT4?g_:(XTOT4-1); pf11=x4[g_]; \
    g_=(base)+768+lane; g_=g_<XTOT4?g_:(XTOT4-1); pf12=x4[g_]; }
#define COMMIT { t4[  0+lane]=pf0;  t4[ 64+lane]=pf1;  t4[128+lane]=pf2; \
                 t4[192+lane]=pf3;  t4[256+lane]=pf4;  t4[320+lane]=pf5; \
                 t4[384+lane]=pf6;  t4[448+lane]=pf7;  t4[512+lane]=pf8; \
                 t4[576+lane]=pf9;  t4[640+lane]=pf10; t4[704+lane]=pf11; \
                 if (lane < 16) t4[768+lane]=pf12; }
#define ROWDOT(dst) { float d_ = row_dot(&xt_[lane * FEAT], Wl); \
                      dst = fmaxf(d_ + bl0, 0.0f); }

    float xa, xb;
    PFALL(sbase)              COMMIT  ROWDOT(xa)       // chunk 0
    PFALL(sbase + ROWF4)      COMMIT  ROWDOT(xb)       // chunk 1
    PFALL(sbase + 2 * ROWF4)                           // chunk 2 in regs

#pragma unroll 1
    for (int t = 0; t <= T_STEPS; ++t) {
        if ((t & 63) == 0 && t > 0 && t < T_STEPS) {
            const int k = t >> 6;
            xa = xb;
            COMMIT                                     // chunk k+1 -> x-tile
            ROWDOT(xb)                                 // precompute chunk k+1
            PFALL(sbase + (k + 2) * ROWF4)             // chunk k+2 in flight
        }
        const float xt = rl(xa, t & 63);

        // ---- 4 gate preacts: 8 interleaved dot2 chains (even/odd split) ----
        float a0A = fmaf(wx0, xt, b0), a0B = 0.0f;
        float a1A = fmaf(wx1, xt, b1), a1B = 0.0f;
        float a2A = fmaf(wx2, xt, b2), a2B = 0.0f;
        float a3A = fmaf(wx3, xt, b3), a3B = 0.0f;
#define DOT(j) { if ((j) & 1) { a0B = dot2(w0_##j, sh_##j, a0B); a1B = dot2(w1_##j, sh_##j, a1B); \
                                a2B = dot2(w2_##j, sh_##j, a2B); a3B = dot2(w3_##j, sh_##j, a3B); } \
                 else         { a0A = dot2(w0_##j, sh_##j, a0A); a1A = dot2(w1_##j, sh_##j, a1A); \
                                a2A = dot2(w2_##j, sh_##j, a2A); a3A = dot2(w3_##j, sh_##j, a3A); } }
        REP26(DOT)

        // ---- lane-local activations + state update (no exchange needed) ----
        const float gi = sigmoidf_fast(a0A + a0B);
        const float gf = sigmoidf_fast(a1A + a1B);
        const float gg = tanhf_fast(a2A + a2B);
        const float go = sigmoidf_fast(a3A + a3B);

        c = fmaf(gf, c, gi * gg);
        h = go * tanhf_fast(c);
        if (t == 0 && lane >= HID) { c = 0.0f; h = 0.0f; }   // LSTM2 zero init (skew)

        // ---- output: lane 51's h2 -> ob slot (t-1)&63 (exec-masked ds_write) ----
        if (lane == HID && t > 0) ob[(t - 1) & 63] = fmaf(h, wav, bav);

        // ---- h broadcast: f16 cvt + quad_perm neighbor + 26 readlanes ----
        int hz = (int)(unsigned)__builtin_bit_cast(unsigned short, (_Float16)h);
        int nb = __builtin_amdgcn_mov_dpp(hz, 0xB1, 0xF, 0xF, true);  // lane r <-> r^1
        int pair = hz | (nb << 16);
#define BCAST(j) sh_##j = rli(pair, 2 * (j));
        REP26(BCAST)

        // coalesced flush of the previous 64 outputs (slot 63 just written)
        if ((t & 63) == 0 && t > 0) optr[t - 64 + lane] = ob[lane];
    }

    // final partial flush: outs 1984..1999 live in slots 0..15
    if (lane < 16) optr[1984 + lane] = ob[lane];
}

extern "C" void kernel_launch(void* const* d_in, const int* in_sizes, int n_in,
                              void* d_out, int out_size, void* d_ws, size_t ws_size,
                              hipStream_t stream) {
    const float* x    = (const float*)d_in[0];
    const float* Wl   = (const float*)d_in[1];
    const float* bl   = (const float*)d_in[2];
    const float* Wih1 = (const float*)d_in[3];
    const float* Whh1 = (const float*)d_in[4];
    const float* bih1 = (const float*)d_in[5];
    const float* bhh1 = (const float*)d_in[6];
    const float* Wih2 = (const float*)d_in[7];
    const float* Whh2 = (const float*)d_in[8];
    const float* bih2 = (const float*)d_in[9];
    const float* bhh2 = (const float*)d_in[10];
    const float* Wa   = (const float*)d_in[11];
    const float* ba   = (const float*)d_in[12];
    float* out = (float*)d_out;

    rnn_kernel<<<NBATCH, 64, 0, stream>>>(x, Wl, bl, Wih1, Whh1, bih1, bhh1,
                                          Wih2, Whh2, bih2, bhh2, Wa, ba, out);
}

// Round 3
// 991.212 us; speedup vs baseline: 1.0145x; 1.0145x over previous
//
#include <hip/hip_runtime.h>

#define T_STEPS 2000
#define NBATCH  256
#define HID     51
#define FEAT    49
#define ROWF4   784                         // float4 per 64-step chunk (64*49/4)
#define XTOT4   (NBATCH * T_STEPS * FEAT / 4)
#define XBUFB   13312                       // 13 * 1024 B staged per chunk (>= 12544)

typedef _Float16 v2h __attribute__((ext_vector_type(2)));

__device__ __forceinline__ float rl(float v, int lane) {
    return __int_as_float(__builtin_amdgcn_readlane(__float_as_int(v), lane));
}
__device__ __forceinline__ int rli(int v, int lane) {
    return __builtin_amdgcn_readlane(v, lane);
}
__device__ __forceinline__ float sigmoidf_fast(float x) {
    return __builtin_amdgcn_rcpf(1.0f + __builtin_amdgcn_exp2f(-1.4426950408889634f * x));
}
__device__ __forceinline__ float tanhf_fast(float x) {
    return 1.0f - 2.0f * __builtin_amdgcn_rcpf(1.0f + __builtin_amdgcn_exp2f(2.8853900817779268f * x));
}
__device__ __forceinline__ int packh2(float lo, float hi) {
    v2h p = (v2h){(_Float16)lo, (_Float16)hi};
    return __builtin_bit_cast(int, p);
}
__device__ __forceinline__ float dot2(int w, int h, float acc) {
    return __builtin_amdgcn_fdot2(__builtin_bit_cast(v2h, w),
                                  __builtin_bit_cast(v2h, h), acc, false);
}
// async global->LDS, 16B per lane: LDS dest = wave-uniform base + lane*16,
// global src = per-lane address. Tracked by vmcnt.
__device__ __forceinline__ void gl_lds16(const void* g, void* l) {
    __builtin_amdgcn_global_load_lds(
        (const __attribute__((address_space(1))) unsigned int*)g,
        (__attribute__((address_space(3))) unsigned int*)l, 16, 0, 0);
}
__device__ __forceinline__ float row_dot(const float* row, const float* __restrict__ Wl) {
    float a0 = 0, a1 = 0, a2 = 0, a3 = 0, a4 = 0, a5 = 0, a6 = 0;
#pragma unroll
    for (int j = 0; j < FEAT; j += 7) {
        a0 = fmaf(row[j    ], Wl[j    ], a0);
        a1 = fmaf(row[j + 1], Wl[j + 1], a1);
        a2 = fmaf(row[j + 2], Wl[j + 2], a2);
        a3 = fmaf(row[j + 3], Wl[j + 3], a3);
        a4 = fmaf(row[j + 4], Wl[j + 4], a4);
        a5 = fmaf(row[j + 5], Wl[j + 5], a5);
        a6 = fmaf(row[j + 6], Wl[j + 6], a6);
    }
    return ((a0 + a1) + (a2 + a3)) + ((a4 + a5) + a6);
}

#define REP26(F) F(0) F(1) F(2) F(3) F(4) F(5) F(6) F(7) F(8) F(9) F(10) F(11) F(12) \
                 F(13) F(14) F(15) F(16) F(17) F(18) F(19) F(20) F(21) F(22) F(23) F(24) F(25)

// SINGLE wave per sample, lane l (<51) owns hidden unit l (all 4 gates);
// lane 51 owns LSTM2 (Whh2 folded into pair-25-hi). Zero barriers.
// x staging now via global_load_lds into a double-buffered LDS tile: no
// prefetch VGPRs (round-2's 13x float4 prefetch forced the 104 weight words
// into AGPR spills -> ~104 extra v_accvgpr_read per step; VGPR_Count=108
// while liveness needed ~170).
__global__ __attribute__((amdgpu_flat_work_group_size(64, 64), amdgpu_waves_per_eu(1)))
void rnn_kernel(
    const float* __restrict__ x,
    const float* __restrict__ Wl, const float* __restrict__ bl,
    const float* __restrict__ Wih1, const float* __restrict__ Whh1,
    const float* __restrict__ bih1, const float* __restrict__ bhh1,
    const float* __restrict__ Wih2, const float* __restrict__ Whh2,
    const float* __restrict__ bih2, const float* __restrict__ bhh2,
    const float* __restrict__ Wa, const float* __restrict__ ba,
    float* __restrict__ out)
{
    const int n    = blockIdx.x;
    const int lane = threadIdx.x;          // 0..63
    float* optr = out + (size_t)n * T_STEPS;
    const float4* x4 = (const float4*)x;
    const int sbase = n * (T_STEPS * FEAT / 4);

    __shared__ __align__(16) char xls[2 * XBUFB];   // double-buffered x-tile
    __shared__ float ob[64];                        // output ring (lane 51 writes)

    // ---- weights: 4 gates x 26 packed f16 pairs per lane ----
#define DECLW(j) int w0_##j, w1_##j, w2_##j, w3_##j; int sh_##j;
    REP26(DECLW)

    const float msk = (lane <= HID) ? 1.0f : 0.0f;   // lanes 52..63 masked to 0
    const float m51 = (lane == HID) ? 1.0f : 0.0f;
#define LOADW(j, wv) { float lo = srow[2*(j)] * msk; \
        float hi = (2*(j)+1 < HID) ? srow[2*(j)+1] * msk : wh2; \
        wv##_##j = packh2(lo, hi); asm("" : "+v"(wv##_##j)); }
#define LOADW0(j) LOADW(j, w0)
#define LOADW1(j) LOADW(j, w1)
#define LOADW2(j) LOADW(j, w2)
#define LOADW3(j) LOADW(j, w3)
    { const float* srow = (lane < HID) ? (Whh1 + (0 * HID + lane) * HID) : (Wih2 + 0 * HID);
      const float wh2 = Whh2[0] * m51;  REP26(LOADW0) }
    { const float* srow = (lane < HID) ? (Whh1 + (1 * HID + lane) * HID) : (Wih2 + 1 * HID);
      const float wh2 = Whh2[1] * m51;  REP26(LOADW1) }
    { const float* srow = (lane < HID) ? (Whh1 + (2 * HID + lane) * HID) : (Wih2 + 2 * HID);
      const float wh2 = Whh2[2] * m51;  REP26(LOADW2) }
    { const float* srow = (lane < HID) ? (Whh1 + (3 * HID + lane) * HID) : (Wih2 + 3 * HID);
      const float wh2 = Whh2[3] * m51;  REP26(LOADW3) }

    float wx0 = 0, wx1 = 0, wx2 = 0, wx3 = 0;
    float b0 = 0, b1 = 0, b2 = 0, b3 = 0;
    if (lane < HID) {
        wx0 = Wih1[0 * HID + lane]; b0 = bih1[0 * HID + lane] + bhh1[0 * HID + lane];
        wx1 = Wih1[1 * HID + lane]; b1 = bih1[1 * HID + lane] + bhh1[1 * HID + lane];
        wx2 = Wih1[2 * HID + lane]; b2 = bih1[2 * HID + lane] + bhh1[2 * HID + lane];
        wx3 = Wih1[3 * HID + lane]; b3 = bih1[3 * HID + lane] + bhh1[3 * HID + lane];
    } else if (lane == HID) {
        b0 = bih2[0] + bhh2[0]; b1 = bih2[1] + bhh2[1];
        b2 = bih2[2] + bhh2[2]; b3 = bih2[3] + bhh2[3];
    }
    const float wav = Wa[0], bav = ba[0];
    const float bl0 = bl[0];

#define INITS(j) sh_##j = 0;
    REP26(INITS)

    float c = 0.0f, h = 0.0f;

    // ---- x staging: 13 x global_load_lds(16B) per 64-step chunk, 0 VGPRs ----
#define STAGE(cbase, buf) { \
    _Pragma("unroll") \
    for (int i_ = 0; i_ < 13; ++i_) { \
        int g_ = (cbase) + i_ * 64 + lane; g_ = g_ < XTOT4 ? g_ : (XTOT4 - 1); \
        gl_lds16(x4 + g_, xls + (buf) * XBUFB + i_ * 1024); \
    } }
#define VMWAIT asm volatile("s_waitcnt vmcnt(0)" ::: "memory");
#define ROWDOT(dst, buf) { \
    const float* row_ = (const float*)(xls + (buf) * XBUFB) + lane * FEAT; \
    float d_ = row_dot(row_, Wl); dst = fmaxf(d_ + bl0, 0.0f); }

    float xa, xb;
    STAGE(sbase, 0)                       // chunk 0 -> buf0
    STAGE(sbase + ROWF4, 1)               // chunk 1 -> buf1
    VMWAIT
    ROWDOT(xa, 0)
    ROWDOT(xb, 1)
    STAGE(sbase + 2 * ROWF4, 0)           // chunk 2 -> buf0 (chunk 0 consumed)

#pragma unroll 1
    for (int t = 0; t <= T_STEPS; ++t) {
        if ((t & 63) == 0 && t > 0 && t < T_STEPS) {
            const int k = t >> 6;
            xa = xb;
            VMWAIT                                   // chunk k+1 stage complete
            ROWDOT(xb, (k + 1) & 1)                  // precompute chunk k+1
            STAGE(sbase + (k + 2) * ROWF4, k & 1)    // chunk k+2 in flight
        }
        const float xt = rl(xa, t & 63);

        // ---- 4 gate preacts: 8 interleaved dot2 chains (even/odd split) ----
        float a0A = fmaf(wx0, xt, b0), a0B = 0.0f;
        float a1A = fmaf(wx1, xt, b1), a1B = 0.0f;
        float a2A = fmaf(wx2, xt, b2), a2B = 0.0f;
        float a3A = fmaf(wx3, xt, b3), a3B = 0.0f;
#define DOT(j) { if ((j) & 1) { a0B = dot2(w0_##j, sh_##j, a0B); a1B = dot2(w1_##j, sh_##j, a1B); \
                                a2B = dot2(w2_##j, sh_##j, a2B); a3B = dot2(w3_##j, sh_##j, a3B); } \
                 else         { a0A = dot2(w0_##j, sh_##j, a0A); a1A = dot2(w1_##j, sh_##j, a1A); \
                                a2A = dot2(w2_##j, sh_##j, a2A); a3A = dot2(w3_##j, sh_##j, a3A); } }
        REP26(DOT)

        // ---- lane-local activations + state update (no exchange needed) ----
        const float gi = sigmoidf_fast(a0A + a0B);
        const float gf = sigmoidf_fast(a1A + a1B);
        const float gg = tanhf_fast(a2A + a2B);
        const float go = sigmoidf_fast(a3A + a3B);

        c = fmaf(gf, c, gi * gg);
        h = go * tanhf_fast(c);
        if (t == 0 && lane >= HID) { c = 0.0f; h = 0.0f; }   // LSTM2 zero init (skew)

        // ---- output: lane 51's h2 -> ob slot (t-1)&63 (exec-masked ds_write) ----
        if (lane == HID && t > 0) ob[(t - 1) & 63] = fmaf(h, wav, bav);

        // ---- h broadcast: f16 cvt + dpp neighbor + 26 readlanes ----
        int hz = (int)(unsigned)__builtin_bit_cast(unsigned short, (_Float16)h);
        int nb = __builtin_amdgcn_mov_dpp(hz, 0xB1, 0xF, 0xF, true);  // lane r <-> r^1
        int pair = hz | (nb << 16);
#define BCAST(j) sh_##j = rli(pair, 2 * (j));
        REP26(BCAST)

        // coalesced flush of the previous 64 outputs (slot 63 just written)
        if ((t & 63) == 0 && t > 0) optr[t - 64 + lane] = ob[lane];
    }

    // final partial flush: outs 1984..1999 live in slots 0..15
    if (lane < 16) optr[1984 + lane] = ob[lane];
}

extern "C" void kernel_launch(void* const* d_in, const int* in_sizes, int n_in,
                              void* d_out, int out_size, void* d_ws, size_t ws_size,
                              hipStream_t stream) {
    const float* x    = (const float*)d_in[0];
    const float* Wl   = (const float*)d_in[1];
    const float* bl   = (const float*)d_in[2];
    const float* Wih1 = (const float*)d_in[3];
    const float* Whh1 = (const float*)d_in[4];
    const float* bih1 = (const float*)d_in[5];
    const float* bhh1 = (const float*)d_in[6];
    const float* Wih2 = (const float*)d_in[7];
    const float* Whh2 = (const float*)d_in[8];
    const float* bih2 = (const float*)d_in[9];
    const float* bhh2 = (const float*)d_in[10];
    const float* Wa   = (const float*)d_in[11];
    const float* ba   = (const float*)d_in[12];
    float* out = (float*)d_out;

    rnn_kernel<<<NBATCH, 64, 0, stream>>>(x, Wl, bl, Wih1, Whh1, bih1, bhh1,
                                          Wih2, Whh2, bih2, bhh2, Wa, ba, out);
}